// Round 8
// baseline (177.969 us; speedup 1.0000x reference)
//
#include <hip/hip_runtime.h>

#define N 8192
#define F 128
#define MARGIN 0.2f
#define NEG_FILL_BITS 0x7149f2cau  // bits of 1e30f
#define NINF (-3.0e38f)
#define PINF (3.0e38f)
#define NUM_IDS 512
#define NWORK 544  // working blocks: sum_{bi<64} ceil((64-bi)/4)

typedef unsigned short ushort_t;
typedef unsigned int uint_t;
typedef _Float16 half8 __attribute__((ext_vector_type(8)));
typedef float f32x4 __attribute__((ext_vector_type(4)));

#define GAS __attribute__((address_space(1)))
#define LAS __attribute__((address_space(3)))

// ---------------------------------------------------------------------------
// ws layout (bytes):
//   [0,    4N)        : pos     (uint)  v=1+hard_pos_d2 (float bits), sorted order
//   [4N,   8N)        : neg     (uint)  v=1+hard_neg_d2 (float bits), sorted order
//   [8N,  12N)        : sid     (int)   sorted ids
//   [12N, 16N)        : na      (float) exact fp32 row norms, sorted order
//   [16N, 16N+2048)   : bincur  (int)   bin cursors
//   [16N+2048, +4)    : donecnt (int)
//   [16N+4096, +2MB)  : H       (fp16)  [N][128] features, sorted order
// acc init = -(na/2+nb/2); MFMA adds S  ->  acc = -d2/2
// ---------------------------------------------------------------------------

__global__ __launch_bounds__(512) void hist_kernel(const int* __restrict__ ids,
                                                   int* __restrict__ bincur,
                                                   int* __restrict__ donecnt) {
    __shared__ int h[NUM_IDS];
    __shared__ int wsum[8];
    const int tid = threadIdx.x;
    if (tid == 0) donecnt[0] = 0;
    h[tid] = 0;
    __syncthreads();
#pragma unroll
    for (int i = 0; i < N / NUM_IDS; ++i) atomicAdd(&h[ids[i * NUM_IDS + tid]], 1);
    __syncthreads();
    int v = h[tid];
    int lane = tid & 63, wv = tid >> 6;
    int s = v;
#pragma unroll
    for (int off = 1; off < 64; off <<= 1) {  // inclusive wave scan
        int t = __shfl_up(s, off, 64);
        if (lane >= off) s += t;
    }
    if (lane == 63) wsum[wv] = s;
    __syncthreads();
    int base = 0;
#pragma unroll
    for (int k = 0; k < 8; ++k) base += (k < wv) ? wsum[k] : 0;
    bincur[tid] = base + s - v;  // exclusive prefix = bin start
}

// Counting-sort scatter + fp16 convert + exact norms + pos/neg init.
__global__ __launch_bounds__(256) void prep_kernel(const float* __restrict__ A,
                                                   const int* __restrict__ ids,
                                                   int* __restrict__ bincur,
                                                   ushort_t* __restrict__ H,
                                                   float* __restrict__ na,
                                                   uint_t* __restrict__ pos,
                                                   uint_t* __restrict__ neg,
                                                   int* __restrict__ sid) {
    int t = blockIdx.x * 256 + threadIdx.x;  // 0 .. N*32-1
    int row = t >> 5, kg = t & 31;
    int lane = threadIdx.x & 63;
    int id = ids[row];
    float4 v = *reinterpret_cast<const float4*>(A + row * F + kg * 4);
    float f[4] = {v.x, v.y, v.z, v.w};
    ushort4 h;
    {
        _Float16 h0 = (_Float16)f[0], h1 = (_Float16)f[1], h2 = (_Float16)f[2], h3 = (_Float16)f[3];
        __builtin_memcpy(&h.x, &h0, 2);
        __builtin_memcpy(&h.y, &h1, 2);
        __builtin_memcpy(&h.z, &h2, 2);
        __builtin_memcpy(&h.w, &h3, 2);
    }
    float s = fmaf(f[0], f[0], fmaf(f[1], f[1], fmaf(f[2], f[2], f[3] * f[3])));
#pragma unroll
    for (int m = 1; m <= 16; m <<= 1) s += __shfl_xor(s, m, 64);  // 32-lane row groups
    int np = 0;
    if ((lane & 31) == 0) np = atomicAdd(&bincur[id], 1);  // sorted position
    np = __shfl(np, lane & 32, 64);                        // broadcast within row group
    *reinterpret_cast<ushort4*>(H + (size_t)np * F + kg * 4) = h;
    if ((lane & 31) == 0) {
        na[np] = s;
        sid[np] = id;
        pos[np] = 0u;
        neg[np] = NEG_FILL_BITS;
    }
}

// Block = strip of up to 4 tiles: rows [bi*128,+128), cols [bj0*128, +4*128).
// A staged to LDS buf0 then pinned in registers; buf0/buf1 become the B
// ping-pong (64 KB LDS total -> 2 blocks/CU). Last working block computes
// the final loss (done-counter fusion).
__global__ __launch_bounds__(512, 4) void hard_mine_mfma(const ushort_t* __restrict__ H,
                                                         const int* __restrict__ sid,
                                                         const float* __restrict__ na,
                                                         uint_t* __restrict__ pos,
                                                         uint_t* __restrict__ neg,
                                                         int* __restrict__ donecnt,
                                                         float* __restrict__ out) {
    __shared__ __align__(16) ushort_t Bs[2][128 * 128];  // 2 x 32 KB (buf0 = A first)
    __shared__ float fsum[8];
    __shared__ int is_last;

    const int bi = blockIdx.x;
    const int bj0 = bi + blockIdx.y * 4;
    if (bj0 > 63) return;  // uniform early exit, before any barrier
    const int ntiles = min(4, 64 - bj0);

    const int tid = threadIdx.x;
    const int w = tid >> 6, lane = tid & 63;
    const int wr = w >> 2, wc = w & 3;  // 2x4 wave grid: wave owns 64x32
    const int lr = lane & 15, lg = lane >> 4;
    const int rowbase = bi * 128;

    // ---- stage A panel -> buf0, B tile0 -> buf1 (rule-21 source swizzle) ----
#pragma unroll
    for (int i = 0; i < 4; ++i) {
        int ci = i * 512 + tid;        // 2048 x 16B chunks
        int r = ci >> 4, sd = ci & 15; // row, 16B-slot
        int sl = sd ^ (r & 7);         // involution on low 3 slot bits
        const ushort_t* ga = H + (size_t)(rowbase + r) * F + sl * 8;
        const ushort_t* gb = H + (size_t)(bj0 * 128 + r) * F + sl * 8;
        __builtin_amdgcn_global_load_lds((const GAS uint_t*)ga, (LAS uint_t*)(Bs[0] + ci * 8),
                                         16, 0, 0);
        __builtin_amdgcn_global_load_lds((const GAS uint_t*)gb, (LAS uint_t*)(Bs[1] + ci * 8),
                                         16, 0, 0);
    }

    // ---- persistent row-side metadata ----
    float na2[4][4];
    int myid[4][4];
#pragma unroll
    for (int m = 0; m < 4; ++m) {
        int r = rowbase + wr * 64 + m * 16 + lg * 4;
        float4 f4 = *reinterpret_cast<const float4*>(na + r);
        int4 i4 = *reinterpret_cast<const int4*>(sid + r);
        na2[m][0] = 0.5f * f4.x; na2[m][1] = 0.5f * f4.y;
        na2[m][2] = 0.5f * f4.z; na2[m][3] = 0.5f * f4.w;
        myid[m][0] = i4.x; myid[m][1] = i4.y; myid[m][2] = i4.z; myid[m][3] = i4.w;
    }
    const int idlast = sid[rowbase + 127];

    float rmx[4][4], pmn[4][4];  // deferred row-side (diff-max / same-min of acc)
#pragma unroll
    for (int m = 0; m < 4; ++m)
#pragma unroll
        for (int q = 0; q < 4; ++q) {
            rmx[m][q] = NINF;
            pmn[m][q] = PINF;
        }

    // ---- tile-0 col metadata ----
    int cb = bj0 * 128;
    float nb2[2];
    int jd[2];
    int jcol0 = sid[cb];
#pragma unroll
    for (int n = 0; n < 2; ++n) {
        int col = cb + wc * 32 + n * 16 + lr;
        nb2[n] = 0.5f * na[col];
        jd[n] = sid[col];
    }

    __syncthreads();  // A + B0 staged (vmcnt drained at barrier)

    // ---- pin A fragments in registers (read buf0 once) ----
    half8 af[4][4];  // [m][ks], 64 VGPR
#pragma unroll
    for (int m = 0; m < 4; ++m) {
        int r = wr * 64 + m * 16 + lr;
#pragma unroll
        for (int ks = 0; ks < 4; ++ks) {
            int ph = (ks * 4 + lg) ^ (r & 7);
            af[m][ks] = *reinterpret_cast<const half8*>(Bs[0] + r * 128 + ph * 8);
        }
    }
    __syncthreads();  // all waves done reading A from buf0 before B1 overwrites it

    for (int tt = 0; tt < ntiles; ++tt) {
        const int bj = bj0 + tt;
        const bool shared_ids = (bi == bj) || (idlast == jcol0);
        ushort_t* cur = Bs[(tt + 1) & 1];  // B(t):  t0 -> buf1
        ushort_t* pre = Bs[tt & 1];        // B(t+1) dest: t0 -> buf0 (freed above)

        // ---- prefetch B(t+1) straight to LDS (no VGPRs) + next col metadata ----
        float nb2n[2] = {0.0f, 0.0f};
        int jdn[2] = {0, 0}, jcol0n = 0;
        if (tt + 1 < ntiles) {
            int cbn = cb + 128;
#pragma unroll
            for (int i = 0; i < 4; ++i) {
                int ci = i * 512 + tid;
                int r = ci >> 4, sd = ci & 15;
                int sl = sd ^ (r & 7);
                const ushort_t* gb = H + (size_t)(cbn + r) * F + sl * 8;
                __builtin_amdgcn_global_load_lds((const GAS uint_t*)gb,
                                                 (LAS uint_t*)(pre + ci * 8), 16, 0, 0);
            }
            jcol0n = sid[cbn];
#pragma unroll
            for (int n = 0; n < 2; ++n) {
                int col = cbn + wc * 32 + n * 16 + lr;
                nb2n[n] = 0.5f * na[col];
                jdn[n] = sid[col];
            }
        }

        // ---- B fragments for current tile ----
        half8 bfr[2][4];
#pragma unroll
        for (int n = 0; n < 2; ++n) {
            int c = wc * 32 + n * 16 + lr;
#pragma unroll
            for (int ks = 0; ks < 4; ++ks) {
                int ph = (ks * 4 + lg) ^ (c & 7);
                bfr[n][ks] = *reinterpret_cast<const half8*>(cur + c * 128 + ph * 8);
            }
        }

        // ---- acc init with folded norms, then K=128 MFMA ----
        f32x4 acc[4][2];
#pragma unroll
        for (int m = 0; m < 4; ++m)
#pragma unroll
            for (int n = 0; n < 2; ++n)
#pragma unroll
                for (int q = 0; q < 4; ++q)
                    acc[m][n][q] = -(na2[m][q] + nb2[n]);
#pragma unroll
        for (int ks = 0; ks < 4; ++ks)
#pragma unroll
            for (int m = 0; m < 4; ++m)
#pragma unroll
                for (int n = 0; n < 2; ++n)
                    acc[m][n] = __builtin_amdgcn_mfma_f32_16x16x32_f16(af[m][ks], bfr[n][ks],
                                                                      acc[m][n], 0, 0, 0);

        // ---- mining epilogue on acc (= -d2/2) ----
        float cmx[2], cpm[2];
#pragma unroll
        for (int n = 0; n < 2; ++n) {
            cmx[n] = NINF;
            cpm[n] = PINF;
        }
        if (!shared_ids) {
#pragma unroll
            for (int n = 0; n < 2; ++n)
#pragma unroll
                for (int m = 0; m < 4; ++m)
#pragma unroll
                    for (int q = 0; q < 4; ++q) {
                        float a = acc[m][n][q];
                        rmx[m][q] = fmaxf(rmx[m][q], a);
                        cmx[n] = fmaxf(cmx[n], a);
                    }
        } else {
#pragma unroll
            for (int n = 0; n < 2; ++n) {
                const int jdv = jd[n];
#pragma unroll
                for (int m = 0; m < 4; ++m)
#pragma unroll
                    for (int q = 0; q < 4; ++q) {
                        float a = acc[m][n][q];
                        bool same = (jdv == myid[m][q]);
                        float tn = same ? NINF : a;
                        float tp = same ? a : PINF;
                        rmx[m][q] = fmaxf(rmx[m][q], tn);
                        pmn[m][q] = fminf(pmn[m][q], tp);
                        cmx[n] = fmaxf(cmx[n], tn);
                        cpm[n] = fminf(cpm[n], tp);
                    }
            }
        }

        // col-side reduce across the 4 lg groups + direct global atomics
#pragma unroll
        for (int mk = 16; mk < 64; mk <<= 1)
#pragma unroll
            for (int n = 0; n < 2; ++n) {
                cmx[n] = fmaxf(cmx[n], __shfl_xor(cmx[n], mk, 64));
                if (shared_ids) cpm[n] = fminf(cpm[n], __shfl_xor(cpm[n], mk, 64));
            }
        if (lg == 0) {
#pragma unroll
            for (int n = 0; n < 2; ++n) {
                int col = cb + wc * 32 + n * 16 + lr;
                float vn = fmaf(-2.0f, cmx[n], 1.0f);  // NINF -> +inf, neutral for min
                atomicMin(&neg[col], __float_as_uint(vn));
                if (shared_ids) {
                    float vp = fmaxf(fmaf(-2.0f, cpm[n], 1.0f), 0.0f);  // PINF -> 0 neutral
                    atomicMax(&pos[col], __float_as_uint(vp));
                }
            }
        }

        __syncthreads();  // B(t+1) staging drained (hidden under this tile's compute)
        cb += 128;
        jcol0 = jcol0n;
#pragma unroll
        for (int n = 0; n < 2; ++n) {
            nb2[n] = nb2n[n];
            jd[n] = jdn[n];
        }
    }

    // ---- deferred row-side reduce (across lr lanes) + atomics ----
#pragma unroll
    for (int mk = 1; mk < 16; mk <<= 1)
#pragma unroll
        for (int m = 0; m < 4; ++m)
#pragma unroll
            for (int q = 0; q < 4; ++q) {
                rmx[m][q] = fmaxf(rmx[m][q], __shfl_xor(rmx[m][q], mk, 64));
                pmn[m][q] = fminf(pmn[m][q], __shfl_xor(pmn[m][q], mk, 64));
            }
    if (lr == 0) {
#pragma unroll
        for (int m = 0; m < 4; ++m)
#pragma unroll
            for (int q = 0; q < 4; ++q) {
                int r = rowbase + wr * 64 + m * 16 + lg * 4 + q;
                float vn = fmaf(-2.0f, rmx[m][q], 1.0f);
                float vp = fmaxf(fmaf(-2.0f, pmn[m][q], 1.0f), 0.0f);
                atomicMin(&neg[r], __float_as_uint(vn));
                atomicMax(&pos[r], __float_as_uint(vp));
            }
    }

    // ---- done-counter: last working block computes the final loss ----
    __syncthreads();  // all this block's atomics drained (vmcnt0 at barrier)
    if (tid == 0) {
        __threadfence();
        int c = __hip_atomic_fetch_add(donecnt, 1, __ATOMIC_ACQ_REL, __HIP_MEMORY_SCOPE_AGENT);
        is_last = (c == NWORK - 1);
    }
    __syncthreads();
    if (!is_last) return;
    __threadfence();

    float s = 0.0f;
#pragma unroll
    for (int i = 0; i < N / 512; ++i) {
        int r = tid + i * 512;
        uint_t up = __hip_atomic_load(&pos[r], __ATOMIC_RELAXED, __HIP_MEMORY_SCOPE_AGENT);
        uint_t un = __hip_atomic_load(&neg[r], __ATOMIC_RELAXED, __HIP_MEMORY_SCOPE_AGENT);
        float vp = __uint_as_float(up);
        float vn = __uint_as_float(un);  // 1e30 if no negatives -> loss 0
        float hp = sqrtf(fmaxf(vp - 1.0f, 0.0f) + 1e-12f);
        float hn = sqrtf(fmaxf(vn - 1.0f, 0.0f) + 1e-12f);
        s += fmaxf(MARGIN + hp - hn, 0.0f);
    }
#pragma unroll
    for (int m = 32; m >= 1; m >>= 1) s += __shfl_xor(s, m, 64);
    if (lane == 0) fsum[w] = s;
    __syncthreads();
    if (tid == 0) {
        float v = 0.0f;
#pragma unroll
        for (int k = 0; k < 8; ++k) v += fsum[k];
        out[0] = v * (1.0f / (float)N);  // LOSS_FACTOR == 1
    }
}

extern "C" void kernel_launch(void* const* d_in, const int* in_sizes, int n_in,
                              void* d_out, int out_size, void* d_ws, size_t ws_size,
                              hipStream_t stream) {
    (void)in_sizes; (void)n_in; (void)out_size; (void)ws_size;
    const float* A = (const float*)d_in[0];
    const int* ids = (const int*)d_in[1];
    float* out = (float*)d_out;

    char* ws = (char*)d_ws;
    uint_t* pos = (uint_t*)ws;
    uint_t* neg = (uint_t*)(ws + 4 * N);
    int* sid = (int*)(ws + 8 * N);
    float* na = (float*)(ws + 12 * N);
    int* bincur = (int*)(ws + 16 * N);
    int* donecnt = (int*)(ws + 16 * N + 2048);
    ushort_t* H = (ushort_t*)(ws + 16 * N + 4096);

    hist_kernel<<<1, 512, 0, stream>>>(ids, bincur, donecnt);
    prep_kernel<<<N * 32 / 256, 256, 0, stream>>>(A, ids, bincur, H, na, pos, neg, sid);
    dim3 grid(64, 16);
    hard_mine_mfma<<<grid, 512, 0, stream>>>(H, sid, na, pos, neg, donecnt, out);
}

// Round 9
// 74.901 us; speedup vs baseline: 2.3761x; 2.3761x over previous
//
#include <hip/hip_runtime.h>

#define N 8192
#define F 128
#define MARGIN 0.2f
#define NEG_FILL_BITS 0x7149f2cau  // bits of 1e30f
#define NINF (-3.0e38f)
#define PINF (3.0e38f)
#define NUM_IDS 512
#define NWORK 544  // working blocks: sum_{bi<64} ceil((64-bi)/4)

typedef unsigned short ushort_t;
typedef unsigned int uint_t;
typedef _Float16 half8 __attribute__((ext_vector_type(8)));
typedef float f32x4 __attribute__((ext_vector_type(4)));

#define GAS __attribute__((address_space(1)))
#define LAS __attribute__((address_space(3)))

// ---------------------------------------------------------------------------
// ws layout (bytes):
//   [0,    4N)        : pos     (uint)  v=1+hard_pos_d2 (float bits), sorted order
//   [4N,   8N)        : neg     (uint)  v=1+hard_neg_d2 (float bits), sorted order
//   [8N,  12N)        : sid     (int)   sorted ids
//   [12N, 16N)        : na      (float) exact fp32 row norms, sorted order
//   [16N, 16N+2048)   : bincur  (int)   bin cursors
//   [16N+2048, +4)    : donecnt (int)
//   [16N+4096, +2MB)  : H       (fp16)  [N][128] features, sorted order
// acc init = -(na/2+nb/2); MFMA adds S  ->  acc = -d2/2
// ---------------------------------------------------------------------------

__global__ __launch_bounds__(512) void hist_kernel(const int* __restrict__ ids,
                                                   int* __restrict__ bincur,
                                                   int* __restrict__ donecnt) {
    __shared__ int h[NUM_IDS];
    __shared__ int wsum[8];
    const int tid = threadIdx.x;
    if (tid == 0) donecnt[0] = 0;
    h[tid] = 0;
    __syncthreads();
#pragma unroll
    for (int i = 0; i < N / NUM_IDS; ++i) atomicAdd(&h[ids[i * NUM_IDS + tid]], 1);
    __syncthreads();
    int v = h[tid];
    int lane = tid & 63, wv = tid >> 6;
    int s = v;
#pragma unroll
    for (int off = 1; off < 64; off <<= 1) {  // inclusive wave scan
        int t = __shfl_up(s, off, 64);
        if (lane >= off) s += t;
    }
    if (lane == 63) wsum[wv] = s;
    __syncthreads();
    int base = 0;
#pragma unroll
    for (int k = 0; k < 8; ++k) base += (k < wv) ? wsum[k] : 0;
    bincur[tid] = base + s - v;  // exclusive prefix = bin start
}

// Counting-sort scatter + fp16 convert + exact norms + pos/neg init.
__global__ __launch_bounds__(256) void prep_kernel(const float* __restrict__ A,
                                                   const int* __restrict__ ids,
                                                   int* __restrict__ bincur,
                                                   ushort_t* __restrict__ H,
                                                   float* __restrict__ na,
                                                   uint_t* __restrict__ pos,
                                                   uint_t* __restrict__ neg,
                                                   int* __restrict__ sid) {
    int t = blockIdx.x * 256 + threadIdx.x;  // 0 .. N*32-1
    int row = t >> 5, kg = t & 31;
    int lane = threadIdx.x & 63;
    int id = ids[row];
    float4 v = *reinterpret_cast<const float4*>(A + row * F + kg * 4);
    float f[4] = {v.x, v.y, v.z, v.w};
    ushort4 h;
    {
        _Float16 h0 = (_Float16)f[0], h1 = (_Float16)f[1], h2 = (_Float16)f[2], h3 = (_Float16)f[3];
        __builtin_memcpy(&h.x, &h0, 2);
        __builtin_memcpy(&h.y, &h1, 2);
        __builtin_memcpy(&h.z, &h2, 2);
        __builtin_memcpy(&h.w, &h3, 2);
    }
    float s = fmaf(f[0], f[0], fmaf(f[1], f[1], fmaf(f[2], f[2], f[3] * f[3])));
#pragma unroll
    for (int m = 1; m <= 16; m <<= 1) s += __shfl_xor(s, m, 64);  // 32-lane row groups
    int np = 0;
    if ((lane & 31) == 0) np = atomicAdd(&bincur[id], 1);  // sorted position
    np = __shfl(np, lane & 32, 64);                        // broadcast within row group
    *reinterpret_cast<ushort4*>(H + (size_t)np * F + kg * 4) = h;
    if ((lane & 31) == 0) {
        na[np] = s;
        sid[np] = id;
        pos[np] = 0u;
        neg[np] = NEG_FILL_BITS;
    }
}

// Block = strip of up to 4 tiles: rows [bi*128,+128), cols [bj0*128, +4*128).
// A staged to LDS buf0 then pinned in registers; buf0/buf1 become the B
// ping-pong (64 KB LDS -> 2 blocks/CU). NO min-waves launch bound: the
// (512,4) variant capped arch-VGPRs at 64 and spilled everything (R8).
__global__ __launch_bounds__(512) void hard_mine_mfma(const ushort_t* __restrict__ H,
                                                      const int* __restrict__ sid,
                                                      const float* __restrict__ na,
                                                      uint_t* __restrict__ pos,
                                                      uint_t* __restrict__ neg,
                                                      int* __restrict__ donecnt,
                                                      float* __restrict__ out) {
    __shared__ __align__(16) ushort_t Bs[2][128 * 128];  // 2 x 32 KB (buf0 = A first)
    __shared__ float fsum[8];
    __shared__ int is_last;

    const int bi = blockIdx.x;
    const int bj0 = bi + blockIdx.y * 4;
    if (bj0 > 63) return;  // uniform early exit, before any barrier
    const int ntiles = min(4, 64 - bj0);

    const int tid = threadIdx.x;
    const int w = tid >> 6, lane = tid & 63;
    const int wr = w >> 2, wc = w & 3;  // 2x4 wave grid: wave owns 64x32
    const int lr = lane & 15, lg = lane >> 4;
    const int rowbase = bi * 128;

    // ---- stage A panel -> buf0, B tile0 -> buf1 (rule-21 source swizzle) ----
#pragma unroll
    for (int i = 0; i < 4; ++i) {
        int ci = i * 512 + tid;        // 2048 x 16B chunks
        int r = ci >> 4, sd = ci & 15; // row, 16B-slot
        int sl = sd ^ (r & 7);         // involution on low 3 slot bits
        const ushort_t* ga = H + (size_t)(rowbase + r) * F + sl * 8;
        const ushort_t* gb = H + (size_t)(bj0 * 128 + r) * F + sl * 8;
        __builtin_amdgcn_global_load_lds((const GAS uint_t*)ga, (LAS uint_t*)(Bs[0] + ci * 8),
                                         16, 0, 0);
        __builtin_amdgcn_global_load_lds((const GAS uint_t*)gb, (LAS uint_t*)(Bs[1] + ci * 8),
                                         16, 0, 0);
    }

    // ---- persistent row-side metadata ----
    float na2[4][4];
    int myid[4][4];
#pragma unroll
    for (int m = 0; m < 4; ++m) {
        int r = rowbase + wr * 64 + m * 16 + lg * 4;
        float4 f4 = *reinterpret_cast<const float4*>(na + r);
        int4 i4 = *reinterpret_cast<const int4*>(sid + r);
        na2[m][0] = 0.5f * f4.x; na2[m][1] = 0.5f * f4.y;
        na2[m][2] = 0.5f * f4.z; na2[m][3] = 0.5f * f4.w;
        myid[m][0] = i4.x; myid[m][1] = i4.y; myid[m][2] = i4.z; myid[m][3] = i4.w;
    }
    const int idlast = sid[rowbase + 127];

    float rmx[4][4], pmn[4][4];  // deferred row-side (diff-max / same-min of acc)
#pragma unroll
    for (int m = 0; m < 4; ++m)
#pragma unroll
        for (int q = 0; q < 4; ++q) {
            rmx[m][q] = NINF;
            pmn[m][q] = PINF;
        }

    // ---- tile-0 col metadata ----
    int cb = bj0 * 128;
    float nb2[2];
    int jd[2];
    int jcol0 = sid[cb];
#pragma unroll
    for (int n = 0; n < 2; ++n) {
        int col = cb + wc * 32 + n * 16 + lr;
        nb2[n] = 0.5f * na[col];
        jd[n] = sid[col];
    }

    __syncthreads();  // A + B0 staged (vmcnt drained at barrier)

    // ---- pin A fragments in registers (read buf0 once) ----
    half8 af[4][4];  // [m][ks], 64 VGPR
#pragma unroll
    for (int m = 0; m < 4; ++m) {
        int r = wr * 64 + m * 16 + lr;
#pragma unroll
        for (int ks = 0; ks < 4; ++ks) {
            int ph = (ks * 4 + lg) ^ (r & 7);
            af[m][ks] = *reinterpret_cast<const half8*>(Bs[0] + r * 128 + ph * 8);
        }
    }
    __syncthreads();  // all waves done reading A from buf0 before B1 overwrites it

    for (int tt = 0; tt < ntiles; ++tt) {
        const int bj = bj0 + tt;
        const bool shared_ids = (bi == bj) || (idlast == jcol0);
        ushort_t* cur = Bs[(tt + 1) & 1];  // B(t):  t0 -> buf1
        ushort_t* pre = Bs[tt & 1];        // B(t+1) dest: t0 -> buf0 (freed above)

        // ---- prefetch B(t+1) straight to LDS (no VGPRs) + next col metadata ----
        float nb2n[2] = {0.0f, 0.0f};
        int jdn[2] = {0, 0}, jcol0n = 0;
        if (tt + 1 < ntiles) {
            int cbn = cb + 128;
#pragma unroll
            for (int i = 0; i < 4; ++i) {
                int ci = i * 512 + tid;
                int r = ci >> 4, sd = ci & 15;
                int sl = sd ^ (r & 7);
                const ushort_t* gb = H + (size_t)(cbn + r) * F + sl * 8;
                __builtin_amdgcn_global_load_lds((const GAS uint_t*)gb,
                                                 (LAS uint_t*)(pre + ci * 8), 16, 0, 0);
            }
            jcol0n = sid[cbn];
#pragma unroll
            for (int n = 0; n < 2; ++n) {
                int col = cbn + wc * 32 + n * 16 + lr;
                nb2n[n] = 0.5f * na[col];
                jdn[n] = sid[col];
            }
        }

        // ---- B fragments for current tile ----
        half8 bfr[2][4];
#pragma unroll
        for (int n = 0; n < 2; ++n) {
            int c = wc * 32 + n * 16 + lr;
#pragma unroll
            for (int ks = 0; ks < 4; ++ks) {
                int ph = (ks * 4 + lg) ^ (c & 7);
                bfr[n][ks] = *reinterpret_cast<const half8*>(cur + c * 128 + ph * 8);
            }
        }

        // ---- acc init with folded norms, then K=128 MFMA ----
        f32x4 acc[4][2];
#pragma unroll
        for (int m = 0; m < 4; ++m)
#pragma unroll
            for (int n = 0; n < 2; ++n)
#pragma unroll
                for (int q = 0; q < 4; ++q)
                    acc[m][n][q] = -(na2[m][q] + nb2[n]);
#pragma unroll
        for (int ks = 0; ks < 4; ++ks)
#pragma unroll
            for (int m = 0; m < 4; ++m)
#pragma unroll
                for (int n = 0; n < 2; ++n)
                    acc[m][n] = __builtin_amdgcn_mfma_f32_16x16x32_f16(af[m][ks], bfr[n][ks],
                                                                      acc[m][n], 0, 0, 0);

        // ---- mining epilogue on acc (= -d2/2) ----
        float cmx[2], cpm[2];
#pragma unroll
        for (int n = 0; n < 2; ++n) {
            cmx[n] = NINF;
            cpm[n] = PINF;
        }
        if (!shared_ids) {
#pragma unroll
            for (int n = 0; n < 2; ++n)
#pragma unroll
                for (int m = 0; m < 4; ++m)
#pragma unroll
                    for (int q = 0; q < 4; ++q) {
                        float a = acc[m][n][q];
                        rmx[m][q] = fmaxf(rmx[m][q], a);
                        cmx[n] = fmaxf(cmx[n], a);
                    }
        } else {
#pragma unroll
            for (int n = 0; n < 2; ++n) {
                const int jdv = jd[n];
#pragma unroll
                for (int m = 0; m < 4; ++m)
#pragma unroll
                    for (int q = 0; q < 4; ++q) {
                        float a = acc[m][n][q];
                        bool same = (jdv == myid[m][q]);
                        float tn = same ? NINF : a;
                        float tp = same ? a : PINF;
                        rmx[m][q] = fmaxf(rmx[m][q], tn);
                        pmn[m][q] = fminf(pmn[m][q], tp);
                        cmx[n] = fmaxf(cmx[n], tn);
                        cpm[n] = fminf(cpm[n], tp);
                    }
            }
        }

        // col-side reduce across the 4 lg groups + direct global atomics
#pragma unroll
        for (int mk = 16; mk < 64; mk <<= 1)
#pragma unroll
            for (int n = 0; n < 2; ++n) {
                cmx[n] = fmaxf(cmx[n], __shfl_xor(cmx[n], mk, 64));
                if (shared_ids) cpm[n] = fminf(cpm[n], __shfl_xor(cpm[n], mk, 64));
            }
        if (lg == 0) {
#pragma unroll
            for (int n = 0; n < 2; ++n) {
                int col = cb + wc * 32 + n * 16 + lr;
                float vn = fmaf(-2.0f, cmx[n], 1.0f);  // NINF -> +inf, neutral for min
                atomicMin(&neg[col], __float_as_uint(vn));
                if (shared_ids) {
                    float vp = fmaxf(fmaf(-2.0f, cpm[n], 1.0f), 0.0f);  // PINF -> 0 neutral
                    atomicMax(&pos[col], __float_as_uint(vp));
                }
            }
        }

        __syncthreads();  // B(t+1) staging drained (hidden under this tile's compute)
        cb += 128;
        jcol0 = jcol0n;
#pragma unroll
        for (int n = 0; n < 2; ++n) {
            nb2[n] = nb2n[n];
            jd[n] = jdn[n];
        }
    }

    // ---- deferred row-side reduce (across lr lanes) + atomics ----
#pragma unroll
    for (int mk = 1; mk < 16; mk <<= 1)
#pragma unroll
        for (int m = 0; m < 4; ++m)
#pragma unroll
            for (int q = 0; q < 4; ++q) {
                rmx[m][q] = fmaxf(rmx[m][q], __shfl_xor(rmx[m][q], mk, 64));
                pmn[m][q] = fminf(pmn[m][q], __shfl_xor(pmn[m][q], mk, 64));
            }
    if (lr == 0) {
#pragma unroll
        for (int m = 0; m < 4; ++m)
#pragma unroll
            for (int q = 0; q < 4; ++q) {
                int r = rowbase + wr * 64 + m * 16 + lg * 4 + q;
                float vn = fmaf(-2.0f, rmx[m][q], 1.0f);
                float vp = fmaxf(fmaf(-2.0f, pmn[m][q], 1.0f), 0.0f);
                atomicMin(&neg[r], __float_as_uint(vn));
                atomicMax(&pos[r], __float_as_uint(vp));
            }
    }

    // ---- done-counter: last working block computes the final loss ----
    __syncthreads();  // all this block's atomics drained
    if (tid == 0) {
        __threadfence();
        int c = __hip_atomic_fetch_add(donecnt, 1, __ATOMIC_ACQ_REL, __HIP_MEMORY_SCOPE_AGENT);
        is_last = (c == NWORK - 1);
    }
    __syncthreads();
    if (!is_last) return;
    __threadfence();

    float s = 0.0f;
#pragma unroll
    for (int i = 0; i < N / 512; ++i) {
        int r = tid + i * 512;
        uint_t up = __hip_atomic_load(&pos[r], __ATOMIC_RELAXED, __HIP_MEMORY_SCOPE_AGENT);
        uint_t un = __hip_atomic_load(&neg[r], __ATOMIC_RELAXED, __HIP_MEMORY_SCOPE_AGENT);
        float vp = __uint_as_float(up);
        float vn = __uint_as_float(un);  // 1e30 if no negatives -> loss 0
        float hp = sqrtf(fmaxf(vp - 1.0f, 0.0f) + 1e-12f);
        float hn = sqrtf(fmaxf(vn - 1.0f, 0.0f) + 1e-12f);
        s += fmaxf(MARGIN + hp - hn, 0.0f);
    }
#pragma unroll
    for (int m = 32; m >= 1; m >>= 1) s += __shfl_xor(s, m, 64);
    if (lane == 0) fsum[w] = s;
    __syncthreads();
    if (tid == 0) {
        float v = 0.0f;
#pragma unroll
        for (int k = 0; k < 8; ++k) v += fsum[k];
        out[0] = v * (1.0f / (float)N);  // LOSS_FACTOR == 1
    }
}

extern "C" void kernel_launch(void* const* d_in, const int* in_sizes, int n_in,
                              void* d_out, int out_size, void* d_ws, size_t ws_size,
                              hipStream_t stream) {
    (void)in_sizes; (void)n_in; (void)out_size; (void)ws_size;
    const float* A = (const float*)d_in[0];
    const int* ids = (const int*)d_in[1];
    float* out = (float*)d_out;

    char* ws = (char*)d_ws;
    uint_t* pos = (uint_t*)ws;
    uint_t* neg = (uint_t*)(ws + 4 * N);
    int* sid = (int*)(ws + 8 * N);
    float* na = (float*)(ws + 12 * N);
    int* bincur = (int*)(ws + 16 * N);
    int* donecnt = (int*)(ws + 16 * N + 2048);
    ushort_t* H = (ushort_t*)(ws + 16 * N + 4096);

    hist_kernel<<<1, 512, 0, stream>>>(ids, bincur, donecnt);
    prep_kernel<<<N * 32 / 256, 256, 0, stream>>>(A, ids, bincur, H, na, pos, neg, sid);
    dim3 grid(64, 16);
    hard_mine_mfma<<<grid, 512, 0, stream>>>(H, sid, na, pos, neg, donecnt, out);
}

// Round 10
// 56.895 us; speedup vs baseline: 3.1280x; 1.3165x over previous
//
#include <hip/hip_runtime.h>

#define N 8192
#define F 128
#define MARGIN 0.2f
#define NEG_FILL_BITS 0x7149f2cau  // bits of 1e30f
#define NINF (-3.0e38f)
#define PINF (3.0e38f)
#define NUM_IDS 512
#define NWORK 256  // grid = 64 x 4, all blocks work

typedef unsigned short ushort_t;
typedef unsigned int uint_t;
typedef _Float16 half8 __attribute__((ext_vector_type(8)));
typedef float f32x4 __attribute__((ext_vector_type(4)));

#define GAS __attribute__((address_space(1)))
#define LAS __attribute__((address_space(3)))

// ---------------------------------------------------------------------------
// ws layout (bytes):
//   [0,    4N)        : pos     (uint)  v=1+hard_pos_d2 (float bits), sorted order
//   [4N,   8N)        : neg     (uint)  v=1+hard_neg_d2 (float bits), sorted order
//   [8N,  12N)        : sid     (int)   sorted ids
//   [12N, 16N)        : na      (float) exact fp32 row norms, sorted order
//   [16N, 16N+2048)   : bincur  (int)   bin cursors
//   [16N+2048, +4)    : donecnt (int)
//   [16N+4096, +2MB)  : H       (fp16)  [N][128] features, sorted order
// acc init = -(na/2+nb/2); MFMA adds S  ->  acc = -d2/2
// Full-square: each block mines ROWS only (no col-side work anywhere).
// ---------------------------------------------------------------------------

__global__ __launch_bounds__(512) void hist_kernel(const int* __restrict__ ids,
                                                   int* __restrict__ bincur,
                                                   int* __restrict__ donecnt) {
    __shared__ int h[NUM_IDS];
    __shared__ int wsum[8];
    const int tid = threadIdx.x;
    if (tid == 0) donecnt[0] = 0;
    h[tid] = 0;
    __syncthreads();
#pragma unroll
    for (int i = 0; i < N / NUM_IDS; ++i) atomicAdd(&h[ids[i * NUM_IDS + tid]], 1);
    __syncthreads();
    int v = h[tid];
    int lane = tid & 63, wv = tid >> 6;
    int s = v;
#pragma unroll
    for (int off = 1; off < 64; off <<= 1) {  // inclusive wave scan
        int t = __shfl_up(s, off, 64);
        if (lane >= off) s += t;
    }
    if (lane == 63) wsum[wv] = s;
    __syncthreads();
    int base = 0;
#pragma unroll
    for (int k = 0; k < 8; ++k) base += (k < wv) ? wsum[k] : 0;
    bincur[tid] = base + s - v;  // exclusive prefix = bin start
}

// Counting-sort scatter + fp16 convert + exact norms + pos/neg init.
__global__ __launch_bounds__(256) void prep_kernel(const float* __restrict__ A,
                                                   const int* __restrict__ ids,
                                                   int* __restrict__ bincur,
                                                   ushort_t* __restrict__ H,
                                                   float* __restrict__ na,
                                                   uint_t* __restrict__ pos,
                                                   uint_t* __restrict__ neg,
                                                   int* __restrict__ sid) {
    int t = blockIdx.x * 256 + threadIdx.x;  // 0 .. N*32-1
    int row = t >> 5, kg = t & 31;
    int lane = threadIdx.x & 63;
    int id = ids[row];
    float4 v = *reinterpret_cast<const float4*>(A + row * F + kg * 4);
    float f[4] = {v.x, v.y, v.z, v.w};
    ushort4 h;
    {
        _Float16 h0 = (_Float16)f[0], h1 = (_Float16)f[1], h2 = (_Float16)f[2], h3 = (_Float16)f[3];
        __builtin_memcpy(&h.x, &h0, 2);
        __builtin_memcpy(&h.y, &h1, 2);
        __builtin_memcpy(&h.z, &h2, 2);
        __builtin_memcpy(&h.w, &h3, 2);
    }
    float s = fmaf(f[0], f[0], fmaf(f[1], f[1], fmaf(f[2], f[2], f[3] * f[3])));
#pragma unroll
    for (int m = 1; m <= 16; m <<= 1) s += __shfl_xor(s, m, 64);  // 32-lane row groups
    int np = 0;
    if ((lane & 31) == 0) np = atomicAdd(&bincur[id], 1);  // sorted position
    np = __shfl(np, lane & 32, 64);                        // broadcast within row group
    *reinterpret_cast<ushort4*>(H + (size_t)np * F + kg * 4) = h;
    if ((lane & 31) == 0) {
        na[np] = s;
        sid[np] = id;
        pos[np] = 0u;
        neg[np] = NEG_FILL_BITS;
    }
}

// Block = 128-row strip x 2048-col chunk = 16 tiles, sequential steady-state.
// A staged once (separate buffer) + pinned to regs; B double-buffered via
// global_load_lds; ONE barrier per tile; row-only mining deferred to block end.
__global__ __launch_bounds__(512) void hard_mine_mfma(const ushort_t* __restrict__ H,
                                                      const int* __restrict__ sid,
                                                      const float* __restrict__ na,
                                                      uint_t* __restrict__ pos,
                                                      uint_t* __restrict__ neg,
                                                      int* __restrict__ donecnt,
                                                      float* __restrict__ out) {
    __shared__ __align__(16) ushort_t As[128 * 128];     // 32 KB (never overwritten)
    __shared__ __align__(16) ushort_t Bs[2][128 * 128];  // 2 x 32 KB ping-pong
    __shared__ float fsum[8];
    __shared__ int is_last;

    const int bi = blockIdx.x;
    const int rowbase = bi * 128;
    const int colchunk = blockIdx.y * 2048;

    const int tid = threadIdx.x;
    const int w = tid >> 6, lane = tid & 63;
    const int wr = w >> 2, wc = w & 3;  // 2x4 wave grid: wave owns 64x32
    const int lr = lane & 15, lg = lane >> 4;

    // ---- stage A panel + B tile0 (rule-21: linear LDS dest, swizzled source) ----
#pragma unroll
    for (int i = 0; i < 4; ++i) {
        int ci = i * 512 + tid;        // 2048 x 16B chunks
        int r = ci >> 4, sd = ci & 15; // row, 16B-slot
        int sl = sd ^ (r & 7);         // involution on low 3 slot bits
        const ushort_t* ga = H + (size_t)(rowbase + r) * F + sl * 8;
        const ushort_t* gb = H + (size_t)(colchunk + r) * F + sl * 8;
        __builtin_amdgcn_global_load_lds((const GAS uint_t*)ga, (LAS uint_t*)(As + ci * 8),
                                         16, 0, 0);
        __builtin_amdgcn_global_load_lds((const GAS uint_t*)gb, (LAS uint_t*)(Bs[0] + ci * 8),
                                         16, 0, 0);
    }

    // ---- persistent row-side metadata ----
    float na2[4][4];
    int myid[4][4];
#pragma unroll
    for (int m = 0; m < 4; ++m) {
        int r = rowbase + wr * 64 + m * 16 + lg * 4;
        float4 f4 = *reinterpret_cast<const float4*>(na + r);
        int4 i4 = *reinterpret_cast<const int4*>(sid + r);
        na2[m][0] = 0.5f * f4.x; na2[m][1] = 0.5f * f4.y;
        na2[m][2] = 0.5f * f4.z; na2[m][3] = 0.5f * f4.w;
        myid[m][0] = i4.x; myid[m][1] = i4.y; myid[m][2] = i4.z; myid[m][3] = i4.w;
    }
    const int idlast = sid[rowbase + 127];

    float rmx[4][4], pmn[4][4];  // row-side: diff-max / same-min of acc, whole chunk
#pragma unroll
    for (int m = 0; m < 4; ++m)
#pragma unroll
        for (int q = 0; q < 4; ++q) {
            rmx[m][q] = NINF;
            pmn[m][q] = PINF;
        }

    // ---- tile-0 col metadata ----
    float nb2[2];
    int jd[2];
    int jcol0 = sid[colchunk];
#pragma unroll
    for (int n = 0; n < 2; ++n) {
        int col = colchunk + wc * 32 + n * 16 + lr;
        nb2[n] = 0.5f * na[col];
        jd[n] = sid[col];
    }

    __syncthreads();  // A + B0 staged (vmcnt drained at barrier)

    // ---- pin A fragments in registers (As never overwritten -> no 2nd barrier) ----
    half8 af[4][4];  // [m][ks], 64 VGPR
#pragma unroll
    for (int m = 0; m < 4; ++m) {
        int r = wr * 64 + m * 16 + lr;
#pragma unroll
        for (int ks = 0; ks < 4; ++ks) {
            int ph = (ks * 4 + lg) ^ (r & 7);
            af[m][ks] = *reinterpret_cast<const half8*>(As + r * 128 + ph * 8);
        }
    }

#pragma unroll 2
    for (int tt = 0; tt < 16; ++tt) {
        const int cb = colchunk + tt * 128;
        const bool shf = (bi == blockIdx.y * 16 + tt) || (idlast == jcol0);
        const ushort_t* cur = Bs[tt & 1];
        ushort_t* pre = Bs[(tt + 1) & 1];

        // ---- prefetch B(t+1) straight to LDS + next col metadata ----
        float nb2n[2] = {0.0f, 0.0f};
        int jdn[2] = {0, 0}, jcol0n = 0;
        if (tt + 1 < 16) {
            int cbn = cb + 128;
#pragma unroll
            for (int i = 0; i < 4; ++i) {
                int ci = i * 512 + tid;
                int r = ci >> 4, sd = ci & 15;
                int sl = sd ^ (r & 7);
                const ushort_t* gb = H + (size_t)(cbn + r) * F + sl * 8;
                __builtin_amdgcn_global_load_lds((const GAS uint_t*)gb,
                                                 (LAS uint_t*)(pre + ci * 8), 16, 0, 0);
            }
            jcol0n = sid[cbn];
#pragma unroll
            for (int n = 0; n < 2; ++n) {
                int col = cbn + wc * 32 + n * 16 + lr;
                nb2n[n] = 0.5f * na[col];
                jdn[n] = sid[col];
            }
        }

        // ---- B fragments for current tile ----
        half8 bfr[2][4];
#pragma unroll
        for (int n = 0; n < 2; ++n) {
            int c = wc * 32 + n * 16 + lr;
#pragma unroll
            for (int ks = 0; ks < 4; ++ks) {
                int ph = (ks * 4 + lg) ^ (c & 7);
                bfr[n][ks] = *reinterpret_cast<const half8*>(cur + c * 128 + ph * 8);
            }
        }

        // ---- acc init with folded norms, then K=128 MFMA ----
        f32x4 acc[4][2];
#pragma unroll
        for (int m = 0; m < 4; ++m)
#pragma unroll
            for (int n = 0; n < 2; ++n)
#pragma unroll
                for (int q = 0; q < 4; ++q)
                    acc[m][n][q] = -(na2[m][q] + nb2[n]);
#pragma unroll
        for (int ks = 0; ks < 4; ++ks)
#pragma unroll
            for (int m = 0; m < 4; ++m)
#pragma unroll
                for (int n = 0; n < 2; ++n)
                    acc[m][n] = __builtin_amdgcn_mfma_f32_16x16x32_f16(af[m][ks], bfr[n][ks],
                                                                      acc[m][n], 0, 0, 0);

        // ---- row-only mining: fast path is 32 fmax, no shuffles, no atomics ----
        if (!shf) {
#pragma unroll
            for (int m = 0; m < 4; ++m)
#pragma unroll
                for (int q = 0; q < 4; ++q) {
                    float x0 = fmaxf(acc[m][0][q], acc[m][1][q]);
                    rmx[m][q] = fmaxf(rmx[m][q], x0);
                }
        } else {
#pragma unroll
            for (int n = 0; n < 2; ++n) {
                const int jdv = jd[n];
#pragma unroll
                for (int m = 0; m < 4; ++m)
#pragma unroll
                    for (int q = 0; q < 4; ++q) {
                        float a = acc[m][n][q];
                        bool same = (jdv == myid[m][q]);
                        rmx[m][q] = fmaxf(rmx[m][q], same ? NINF : a);
                        pmn[m][q] = fminf(pmn[m][q], same ? a : PINF);
                    }
            }
        }

        __syncthreads();  // B(t+1) staging drained (hidden under this tile's compute)
        jcol0 = jcol0n;
#pragma unroll
        for (int n = 0; n < 2; ++n) {
            nb2[n] = nb2n[n];
            jd[n] = jdn[n];
        }
    }

    // ---- block-end row reduce (across lr lanes) + atomics ----
#pragma unroll
    for (int mk = 1; mk < 16; mk <<= 1)
#pragma unroll
        for (int m = 0; m < 4; ++m)
#pragma unroll
            for (int q = 0; q < 4; ++q) {
                rmx[m][q] = fmaxf(rmx[m][q], __shfl_xor(rmx[m][q], mk, 64));
                pmn[m][q] = fminf(pmn[m][q], __shfl_xor(pmn[m][q], mk, 64));
            }
    if (lr == 0) {
#pragma unroll
        for (int m = 0; m < 4; ++m)
#pragma unroll
            for (int q = 0; q < 4; ++q) {
                int r = rowbase + wr * 64 + m * 16 + lg * 4 + q;
                float vn = fmaf(-2.0f, rmx[m][q], 1.0f);               // NINF -> +inf neutral
                float vp = fmaxf(fmaf(-2.0f, pmn[m][q], 1.0f), 0.0f);  // PINF -> 0 neutral
                atomicMin(&neg[r], __float_as_uint(vn));
                atomicMax(&pos[r], __float_as_uint(vp));
            }
    }

    // ---- done-counter: last block computes the final loss ----
    __syncthreads();  // all this block's atomics drained
    if (tid == 0) {
        __threadfence();
        int c = __hip_atomic_fetch_add(donecnt, 1, __ATOMIC_ACQ_REL, __HIP_MEMORY_SCOPE_AGENT);
        is_last = (c == NWORK - 1);
    }
    __syncthreads();
    if (!is_last) return;
    __threadfence();

    float s = 0.0f;
#pragma unroll
    for (int i = 0; i < N / 512; ++i) {
        int r = tid + i * 512;
        uint_t up = __hip_atomic_load(&pos[r], __ATOMIC_RELAXED, __HIP_MEMORY_SCOPE_AGENT);
        uint_t un = __hip_atomic_load(&neg[r], __ATOMIC_RELAXED, __HIP_MEMORY_SCOPE_AGENT);
        float vp = __uint_as_float(up);
        float vn = __uint_as_float(un);  // 1e30 if no negatives -> loss 0
        float hp = sqrtf(fmaxf(vp - 1.0f, 0.0f) + 1e-12f);
        float hn = sqrtf(fmaxf(vn - 1.0f, 0.0f) + 1e-12f);
        s += fmaxf(MARGIN + hp - hn, 0.0f);
    }
#pragma unroll
    for (int m = 32; m >= 1; m >>= 1) s += __shfl_xor(s, m, 64);
    if (lane == 0) fsum[w] = s;
    __syncthreads();
    if (tid == 0) {
        float v = 0.0f;
#pragma unroll
        for (int k = 0; k < 8; ++k) v += fsum[k];
        out[0] = v * (1.0f / (float)N);  // LOSS_FACTOR == 1
    }
}

extern "C" void kernel_launch(void* const* d_in, const int* in_sizes, int n_in,
                              void* d_out, int out_size, void* d_ws, size_t ws_size,
                              hipStream_t stream) {
    (void)in_sizes; (void)n_in; (void)out_size; (void)ws_size;
    const float* A = (const float*)d_in[0];
    const int* ids = (const int*)d_in[1];
    float* out = (float*)d_out;

    char* ws = (char*)d_ws;
    uint_t* pos = (uint_t*)ws;
    uint_t* neg = (uint_t*)(ws + 4 * N);
    int* sid = (int*)(ws + 8 * N);
    float* na = (float*)(ws + 12 * N);
    int* bincur = (int*)(ws + 16 * N);
    int* donecnt = (int*)(ws + 16 * N + 2048);
    ushort_t* H = (ushort_t*)(ws + 16 * N + 4096);

    hist_kernel<<<1, 512, 0, stream>>>(ids, bincur, donecnt);
    prep_kernel<<<N * 32 / 256, 256, 0, stream>>>(A, ids, bincur, H, na, pos, neg, sid);
    dim3 grid(64, 4);
    hard_mine_mfma<<<grid, 512, 0, stream>>>(H, sid, na, pos, neg, donecnt, out);
}